// Round 16
// baseline (520.240 us; speedup 1.0000x reference)
//
#include <hip/hip_runtime.h>

typedef __bf16 bf16x4 __attribute__((ext_vector_type(4)));
typedef __bf16 bf16x8 __attribute__((ext_vector_type(8)));
typedef float f32x4 __attribute__((ext_vector_type(4)));

#define MFMA_BF16 __builtin_amdgcn_mfma_f32_16x16x32_bf16

// ---------------------------------------------------------------------------
// prep_xmom: blocks [0,64) accumulate x-moments (Sx[3], Sxx[6]);
// blocks [64,80) convert W2->bf16; [80,208) convert W3->bf16.
// ---------------------------------------------------------------------------
__global__ __launch_bounds__(256) void prep_xmom_kernel(
    const float* __restrict__ x, const float* __restrict__ W2,
    const float* __restrict__ W3, __bf16* __restrict__ W2bf,
    __bf16* __restrict__ W3bf, float* __restrict__ xmom) {
  const int b = blockIdx.x;
  const int t = threadIdx.x;
  if (b >= 64) {
    const float* src;
    __bf16* dst;
    int idx;
    if (b < 80) {
      idx = (b - 64) * 2048 + t * 8;
      src = W2;
      dst = W2bf;
    } else {
      idx = (b - 80) * 2048 + t * 8;
      src = W3;
      dst = W3bf;
    }
    float4 f0 = *(const float4*)(src + idx);
    float4 f1 = *(const float4*)(src + idx + 4);
    bf16x8 o;
    o[0] = (__bf16)f0.x;
    o[1] = (__bf16)f0.y;
    o[2] = (__bf16)f0.z;
    o[3] = (__bf16)f0.w;
    o[4] = (__bf16)f1.x;
    o[5] = (__bf16)f1.y;
    o[6] = (__bf16)f1.z;
    o[7] = (__bf16)f1.w;
    *(bf16x8*)(dst + idx) = o;
    return;
  }
  float m[9] = {};
#pragma unroll 4
  for (int i = 0; i < 16; ++i) {
    int r = b * 4096 + i * 256 + t;
    const float* xp = x + (size_t)r * 3;
    float a = xp[0], bb = xp[1], c = xp[2];
    m[0] += a;
    m[1] += bb;
    m[2] += c;
    m[3] = fmaf(a, a, m[3]);
    m[4] = fmaf(a, bb, m[4]);
    m[5] = fmaf(a, c, m[5]);
    m[6] = fmaf(bb, bb, m[6]);
    m[7] = fmaf(bb, c, m[7]);
    m[8] = fmaf(c, c, m[8]);
  }
  __shared__ float red[4][9];
  int lane = t & 63, wave = t >> 6;
#pragma unroll
  for (int j = 0; j < 9; ++j) {
    float v = m[j];
    v += __shfl_xor(v, 1);
    v += __shfl_xor(v, 2);
    v += __shfl_xor(v, 4);
    v += __shfl_xor(v, 8);
    v += __shfl_xor(v, 16);
    v += __shfl_xor(v, 32);
    if (lane == 0) red[wave][j] = v;
  }
  __syncthreads();
  if (t < 9) atomicAdd(&xmom[t], red[0][t] + red[1][t] + red[2][t] + red[3][t]);
}

// compute BN1 fold coeffs for column c (c < 64) from x-moments
__device__ __forceinline__ void bn1_fold(const float* __restrict__ xm,
                                         const float* __restrict__ W1,
                                         const float* __restrict__ b1,
                                         const float* __restrict__ gamma1,
                                         const float* __restrict__ beta1,
                                         int c, float invN, float fN,
                                         float* f0, float* f1, float* f2,
                                         float* f3) {
  float w0 = W1[c * 3], w1 = W1[c * 3 + 1], w2 = W1[c * 3 + 2], bb = b1[c];
  float wx = w0 * xm[0] + w1 * xm[1] + w2 * xm[2];
  float sy = wx + fN * bb;
  float q = w0 * w0 * xm[3] + 2.f * w0 * w1 * xm[4] + 2.f * w0 * w2 * xm[5] +
            w1 * w1 * xm[6] + 2.f * w1 * w2 * xm[7] + w2 * w2 * xm[8] +
            2.f * bb * wx + fN * bb * bb;
  float mu = sy * invN;
  float var = q * invN - mu * mu;
  float sc = gamma1[c] * rsqrtf(var + 1e-5f);
  float sh = beta1[c] - mu * sc;
  *f0 = sc * w0;
  *f1 = sc * w1;
  *f2 = sc * w2;
  *f3 = sc * bb + sh;
}

// ---------------------------------------------------------------------------
// m1: M1 = sum_r h1_r h1_r^T (64x64), s1 = sum_r h1_r. BN1 from moments.
// ---------------------------------------------------------------------------
__global__ __launch_bounds__(256, 4) void m1_kernel(
    const float* __restrict__ x2, const float* __restrict__ xmom,
    const float* __restrict__ gamma1, const float* __restrict__ beta1,
    const float* __restrict__ W1, const float* __restrict__ b1,
    float* __restrict__ M1, float* __restrict__ s1, float invN, float fN) {
  __shared__ float sF[256];
  __shared__ float xs[768];
  __shared__ __bf16 h1T[64 * 264];  // [col][row], row-pad 264
  __shared__ float s1s[4][64];

  const int t = threadIdx.x;
  const int lane = t & 63, wave = t >> 6;
  const int lrow = lane & 15, lgrp = lane >> 4;

  if (t < 64) {
    float f0, f1, f2, f3;
    bn1_fold(xmom, W1, b1, gamma1, beta1, t, invN, fN, &f0, &f1, &f2, &f3);
    sF[t] = f0;
    sF[64 + t] = f1;
    sF[128 + t] = f2;
    sF[192 + t] = f3;
  }
  if (t < 192)
    ((float4*)xs)[t] = ((const float4*)(x2 + (size_t)blockIdx.x * 768))[t];
  __syncthreads();

  const int c0 = (t & 3) * 16;
  const int r0 = t >> 2;
  float sAcc[16] = {};
#pragma unroll
  for (int s = 0; s < 4; ++s) {
    int r = r0 + s * 64;
    float X0 = xs[r * 3], X1 = xs[r * 3 + 1], X2 = xs[r * 3 + 2];
#pragma unroll
    for (int j = 0; j < 16; ++j) {
      int c = c0 + j;
      float h = fmaxf(
          fmaf(sF[c], X0, fmaf(sF[64 + c], X1, fmaf(sF[128 + c], X2, sF[192 + c]))),
          0.f);
      sAcc[j] += h;
      h1T[c * 264 + r] = (__bf16)h;
    }
  }
  __syncthreads();

  f32x4 acc[4] = {};
#pragma unroll
  for (int kk = 0; kk < 256; kk += 32) {
    bf16x8 af = *(const bf16x8*)&h1T[(wave * 16 + lrow) * 264 + kk + lgrp * 8];
#pragma unroll
    for (int n = 0; n < 4; ++n) {
      bf16x8 bfr = *(const bf16x8*)&h1T[(n * 16 + lrow) * 264 + kk + lgrp * 8];
      acc[n] = MFMA_BF16(af, bfr, acc[n], 0, 0, 0);
    }
  }
#pragma unroll
  for (int n = 0; n < 4; ++n)
#pragma unroll
    for (int rr = 0; rr < 4; ++rr)
      atomicAdd(&M1[(wave * 16 + lgrp * 4 + rr) * 64 + n * 16 + lrow],
                acc[n][rr]);

#pragma unroll
  for (int j = 0; j < 16; ++j) {
    float v = sAcc[j];
    v += __shfl_xor(v, 4);
    v += __shfl_xor(v, 8);
    v += __shfl_xor(v, 16);
    v += __shfl_xor(v, 32);
    if (lane < 4) s1s[wave][(lane & 3) * 16 + j] = v;
  }
  __syncthreads();
  if (t < 64)
    atomicAdd(&s1[t], s1s[0][t] + s1s[1][t] + s1s[2][t] + s1s[3][t]);
}

// ---------------------------------------------------------------------------
// finalize2v: per col c of layer 2, q = w^T M1 w; derive BN2 scale/shiftf.
// ---------------------------------------------------------------------------
__global__ __launch_bounds__(256) void finalize2v_kernel(
    const float* __restrict__ M1, const float* __restrict__ s1,
    const float* __restrict__ W2, const float* __restrict__ b2,
    const float* __restrict__ gamma2, const float* __restrict__ beta2,
    float* __restrict__ scale2, float* __restrict__ shift2f, float fN) {
  __shared__ float sM[64 * 65];
  __shared__ float ss[64];
  int t = threadIdx.x;
  for (int i = t; i < 4096; i += 256) sM[(i >> 6) * 65 + (i & 63)] = M1[i];
  if (t < 64) ss[t] = s1[t];
  __syncthreads();
  int lane = t & 63;
  int col = blockIdx.x * 4 + (t >> 6);
  float wi = W2[(size_t)col * 64 + lane];
  float p = 0.f;
#pragma unroll
  for (int j = 0; j < 64; ++j) p = fmaf(sM[lane * 65 + j], __shfl(wi, j), p);
  float qi = wi * p;
  float swi = ss[lane] * wi;
#pragma unroll
  for (int off = 1; off < 64; off <<= 1) {
    qi += __shfl_xor(qi, off);
    swi += __shfl_xor(swi, off);
  }
  if (lane == 0) {
    float b = b2[col];
    float sy = swi + fN * b;
    float sqs = qi + 2.f * b * swi + fN * b * b;
    float mu = sy / fN;
    float var = sqs / fN - mu * mu;
    float sc = gamma2[col] * rsqrtf(var + 1e-5f);
    scale2[col] = sc;
    shift2f[col] = (beta2[col] - mu * sc) + sc * b;
  }
}

// ---------------------------------------------------------------------------
// Fused kernel, 16 waves (1024 threads), ONE block covers ALL 512 columns:
// wave w owns GEMM3 cols [w*32,+32) and GEMM2 channels [w*32,+32).
// h2 computed ONCE per row-group (was twice via colHalf split).
// Lockstep pipeline, single barrier per rg, double-buffered h1/h2 (MODE 3).
// MODE 3: stats + store y3 bf16 where (rgFirst+g) < rStoreRgs.
// MODE 2 (gCount==1): single-buffered; BN3 inline + ReLU + @W4 -> plain store.
// ---------------------------------------------------------------------------
#define G3_LD(BUF, K)                                                        \
  _Pragma("unroll") for (int m = 0; m < 4; ++m) BUF[m] =                     \
      *(const bf16x8*)&h2r[(m * 16 + lrow) * 520 + (K) * 32 + lgrp * 8];

#define G3_MM(BUF, K)                                                        \
  _Pragma("unroll") for (int m = 0; m < 4; ++m) {                            \
    acc[m][0] = MFMA_BF16(BUF[m], b3r[K][0], acc[m][0], 0, 0, 0);            \
    acc[m][1] = MFMA_BF16(BUF[m], b3r[K][1], acc[m][1], 0, 0, 0);            \
  }

template <int MODE>
__global__ __launch_bounds__(1024, 1) void fused_kernel(
    const float* __restrict__ x2, const float* __restrict__ xmom,
    const float* __restrict__ gamma1, const float* __restrict__ beta1,
    const float* __restrict__ W1, const float* __restrict__ b1,
    const __bf16* __restrict__ W2bf, const float* __restrict__ scale2,
    const float* __restrict__ shift2f, const __bf16* __restrict__ W3bf,
    const float* __restrict__ b3, const float* __restrict__ gamma3,
    const float* __restrict__ beta3, const float* __restrict__ W4,
    const float* __restrict__ b4, float* __restrict__ gsum3,
    float* __restrict__ gsq3, float* __restrict__ out,
    __bf16* __restrict__ y3o, int gBase, int gCount, int rStoreRgs,
    float invN, float fN) {
  constexpr int NB = (MODE == 2) ? 1 : 2;
  __shared__ __bf16 h1buf[NB][64 * 72];    // 9 KB each
  __shared__ __bf16 h2buf[NB][64 * 520];   // 65 KB each
  __shared__ float sF[256];
  __shared__ float sSc2[512], sSh2[512];
  __shared__ float outaccW[(MODE == 2) ? 16 : 1][64][2];

  const int t = threadIdx.x;
  const int lane = t & 63, wave = t >> 6;        // wave 0..15
  const int lrow = lane & 15, lgrp = lane >> 4;
  const int rgFirst = gBase + (int)blockIdx.x * gCount;
  const int wCol = wave * 32;                    // GEMM2 channels & GEMM3 cols

  // ---- one-time LDS staging (BN1 fold from x-moments) ----
  if (t < 64) {
    float f0, f1, f2, f3;
    bn1_fold(xmom, W1, b1, gamma1, beta1, t, invN, fN, &f0, &f1, &f2, &f3);
    sF[t] = f0;
    sF[64 + t] = f1;
    sF[128 + t] = f2;
    sF[192 + t] = f3;
  }
  if (t < 512) {
    sSc2[t] = scale2[t];
    sSh2[t] = shift2f[t];
  }

  // ---- one-time: W2, W3 fragments -> registers ----
  bf16x8 b2r[2][2];
#pragma unroll
  for (int kk = 0; kk < 2; ++kk)
#pragma unroll
    for (int n = 0; n < 2; ++n)
      b2r[kk][n] = *(const bf16x8*)&W2bf[(wCol + n * 16 + lrow) * 64 +
                                         kk * 32 + lgrp * 8];
  bf16x8 b3r[16][2];
#pragma unroll
  for (int k = 0; k < 16; ++k)
#pragma unroll
    for (int n = 0; n < 2; ++n)
      b3r[k][n] = *(const bf16x8*)&W3bf[(size_t)(wCol + n * 16 + lrow) * 512 +
                                        k * 32 + lgrp * 8];

  const int c3a = wCol + lrow, c3b = wCol + 16 + lrow;
  float b3a = 0.f, b3b = 0.f;
  float sc3a = 0.f, sc3b = 0.f, sh3a = 0.f, sh3b = 0.f;
  float w40a = 0.f, w40b = 0.f, w41a = 0.f, w41b = 0.f, B40 = 0.f, B41 = 0.f;
  if (MODE != 2) {
    b3a = b3[c3a];
    b3b = b3[c3b];
  } else {
    float mu = gsum3[c3a] * invN;
    float var = gsq3[c3a] * invN - mu * mu;
    sc3a = gamma3[c3a] * rsqrtf(var + 1e-5f);
    sh3a = sc3a * b3[c3a] + (beta3[c3a] - mu * sc3a);
    mu = gsum3[c3b] * invN;
    var = gsq3[c3b] * invN - mu * mu;
    sc3b = gamma3[c3b] * rsqrtf(var + 1e-5f);
    sh3b = sc3b * b3[c3b] + (beta3[c3b] - mu * sc3b);
    w40a = W4[c3a];
    w40b = W4[c3b];
    w41a = W4[512 + c3a];
    w41b = W4[512 + c3b];
    B40 = b4[0];
    B41 = b4[1];
  }
  float csA = 0.f, cqA = 0.f, csB = 0.f, cqB = 0.f;

  // h1 staging: 1024 threads x 4 elems (bf16x4)
  const int hr = t >> 4, hc0 = (t & 15) * 4;
  const float* xbase = x2 + ((size_t)rgFirst * 64 + hr) * 3;
  float xa, xb, xc;

  auto stageH1 = [&](__bf16* h1p) {
    bf16x4 hv;
#pragma unroll
    for (int j = 0; j < 4; ++j) {
      int c = hc0 + j;
      float h = fmaf(sF[c], xa,
                     fmaf(sF[64 + c], xb, fmaf(sF[128 + c], xc, sF[192 + c])));
      hv[j] = (__bf16)fmaxf(h, 0.f);
    }
    *(bf16x4*)&h1p[hr * 72 + hc0] = hv;
  };

  // GEMM2: wave computes channels [wCol, wCol+32)
  auto gemm2 = [&](const __bf16* h1p, __bf16* h2p) {
    f32x4 a2[2][4] = {};  // [n][m]
#pragma unroll
    for (int kk = 0; kk < 2; ++kk) {
      bf16x8 af0 = *(const bf16x8*)&h1p[(0 * 16 + lrow) * 72 + kk * 32 + lgrp * 8];
      bf16x8 af1 = *(const bf16x8*)&h1p[(1 * 16 + lrow) * 72 + kk * 32 + lgrp * 8];
      bf16x8 af2 = *(const bf16x8*)&h1p[(2 * 16 + lrow) * 72 + kk * 32 + lgrp * 8];
      bf16x8 af3 = *(const bf16x8*)&h1p[(3 * 16 + lrow) * 72 + kk * 32 + lgrp * 8];
#pragma unroll
      for (int n = 0; n < 2; ++n) {
        a2[n][0] = MFMA_BF16(b2r[kk][n], af0, a2[n][0], 0, 0, 0);
        a2[n][1] = MFMA_BF16(b2r[kk][n], af1, a2[n][1], 0, 0, 0);
        a2[n][2] = MFMA_BF16(b2r[kk][n], af2, a2[n][2], 0, 0, 0);
        a2[n][3] = MFMA_BF16(b2r[kk][n], af3, a2[n][3], 0, 0, 0);
      }
    }
#pragma unroll
    for (int n = 0; n < 2; ++n) {
      int ch0 = wCol + n * 16 + lgrp * 4;
      float s0 = sSc2[ch0], s1v = sSc2[ch0 + 1], s2v = sSc2[ch0 + 2],
            s3v = sSc2[ch0 + 3];
      float z0 = sSh2[ch0], z1 = sSh2[ch0 + 1], z2 = sSh2[ch0 + 2],
            z3 = sSh2[ch0 + 3];
#pragma unroll
      for (int m = 0; m < 4; ++m) {
        int row = m * 16 + lrow;
        bf16x4 hv;
        hv[0] = (__bf16)fmaxf(fmaf(s0, a2[n][m][0], z0), 0.f);
        hv[1] = (__bf16)fmaxf(fmaf(s1v, a2[n][m][1], z1), 0.f);
        hv[2] = (__bf16)fmaxf(fmaf(s2v, a2[n][m][2], z2), 0.f);
        hv[3] = (__bf16)fmaxf(fmaf(s3v, a2[n][m][3], z3), 0.f);
        *(bf16x4*)&h2p[row * 520 + ch0] = hv;
      }
    }
  };

  __syncthreads();  // sF/sSc2/sSh2 visible

  // ---- prologue ----
  xa = xbase[0];
  xb = xbase[1];
  xc = xbase[2];
  stageH1(h1buf[0]);
  __syncthreads();  // h1(0) ready
  gemm2(h1buf[0], h2buf[0]);
  if (gCount > 1) {
    const float* xn = xbase + 192;
    xa = xn[0];
    xb = xn[1];
    xc = xn[2];
    stageH1(h1buf[NB - 1]);
  }
  __syncthreads();  // h2(0) + h1(1) ready

  for (int g = 0; g < gCount; ++g) {
    const int rBase = (rgFirst + g) * 64;
    const __bf16* h2r = h2buf[g & (NB - 1)];
    const bool doStore = (MODE == 3) && (rgFirst + g < rStoreRgs);

    // issue x loads for h1(g+2) early
    if (g + 2 < gCount) {
      const float* xn = xbase + (size_t)(g + 2) * 192;
      xa = xn[0];
      xb = xn[1];
      xc = xn[2];
    }

    // GEMM2(g+1) -> h2[(g+1)&1]
    if (g + 1 < gCount)
      gemm2(h1buf[(g + 1) & (NB - 1)], h2buf[(g + 1) & (NB - 1)]);

    // stage h1(g+2) -> h1[g&1]
    if (g + 2 < gCount) stageH1(h1buf[g & (NB - 1)]);

    // ---- GEMM3(g): 2-deep af pipeline, register-B MFMA ----
    f32x4 acc[4][2] = {};  // [m][n]
    bf16x8 afA[4], afB[4];
    G3_LD(afA, 0)
#pragma unroll
    for (int k = 0; k < 16; k += 2) {
      G3_LD(afB, k + 1)
      G3_MM(afA, k)
      if (k < 14) { G3_LD(afA, k + 2) }
      G3_MM(afB, k + 1)
    }

    if (MODE != 2) {
#pragma unroll
      for (int m = 0; m < 4; ++m)
#pragma unroll
        for (int rr = 0; rr < 4; ++rr) {
          float ya = acc[m][0][rr] + b3a;
          float yb = acc[m][1][rr] + b3b;
          csA += ya;
          cqA = fmaf(ya, ya, cqA);
          csB += yb;
          cqB = fmaf(yb, yb, cqB);
          if (doStore) {
            size_t row = (size_t)(rBase + m * 16 + lgrp * 4 + rr);
            y3o[row * 512 + c3a] = (__bf16)ya;
            y3o[row * 512 + c3b] = (__bf16)yb;
          }
        }
    } else {
#pragma unroll
      for (int m = 0; m < 4; ++m)
#pragma unroll
        for (int rr = 0; rr < 4; ++rr) {
          float ha = fmaxf(fmaf(sc3a, acc[m][0][rr], sh3a), 0.f);
          float hb = fmaxf(fmaf(sc3b, acc[m][1][rr], sh3b), 0.f);
          float dd0 = fmaf(ha, w40a, hb * w40b);
          float dd1 = fmaf(ha, w41a, hb * w41b);
          dd0 += __shfl_xor(dd0, 1);
          dd1 += __shfl_xor(dd1, 1);
          dd0 += __shfl_xor(dd0, 2);
          dd1 += __shfl_xor(dd1, 2);
          dd0 += __shfl_xor(dd0, 4);
          dd1 += __shfl_xor(dd1, 4);
          dd0 += __shfl_xor(dd0, 8);
          dd1 += __shfl_xor(dd1, 8);
          if (lrow == 0) {
            int row = m * 16 + lgrp * 4 + rr;
            outaccW[(MODE == 2) ? wave : 0][row][0] = dd0;
            outaccW[(MODE == 2) ? wave : 0][row][1] = dd1;
          }
        }
    }
    __syncthreads();  // single per-rg barrier: all buffers rotate safely
  }

  if (MODE != 2) {
    csA += __shfl_xor(csA, 16);
    cqA += __shfl_xor(cqA, 16);
    csB += __shfl_xor(csB, 16);
    cqB += __shfl_xor(cqB, 16);
    csA += __shfl_xor(csA, 32);
    cqA += __shfl_xor(cqA, 32);
    csB += __shfl_xor(csB, 32);
    cqB += __shfl_xor(cqB, 32);
    if (lgrp == 0) {
      atomicAdd(&gsum3[c3a], csA);
      atomicAdd(&gsq3[c3a], cqA);
      atomicAdd(&gsum3[c3b], csB);
      atomicAdd(&gsq3[c3b], cqB);
    }
  } else {
    // gCount == 1: block covers all 512 cols -> plain store (no atomics)
    if (t < 128) {
      int row = t >> 1, o = t & 1;
      float s = 0.f;
#pragma unroll
      for (int w = 0; w < 16; ++w) s += outaccW[w][row][o];
      out[(size_t)(rgFirst * 64 + row) * 2 + o] = s + ((o == 0) ? B40 : B41);
    }
  }
}

// ---------------------------------------------------------------------------
// stream_out: out = relu(sc3*y3 + sh3) @ W4^T + b4. BN3 finalize inline.
// ---------------------------------------------------------------------------
__global__ __launch_bounds__(256) void stream_out_kernel(
    const __bf16* __restrict__ y3, const float* __restrict__ gsum3,
    const float* __restrict__ gsq3, const float* __restrict__ gamma3,
    const float* __restrict__ beta3, const float* __restrict__ W4,
    const float* __restrict__ b4, float* __restrict__ out, int N, float invN) {
  __shared__ float sSc[512], sSh[512], sW0[512], sW1[512];
  int t = threadIdx.x;
  for (int i = t; i < 512; i += 256) {
    float mu = gsum3[i] * invN;
    float var = gsq3[i] * invN - mu * mu;
    float sc = gamma3[i] * rsqrtf(var + 1e-5f);
    sSc[i] = sc;
    sSh[i] = beta3[i] - mu * sc;  // y3 already includes b3
    sW0[i] = W4[i];
    sW1[i] = W4[512 + i];
  }
  __syncthreads();
  int lane = t & 63, wv = t >> 6;
  int c0 = lane * 8;
  float fsc[8], fsh[8], fw0[8], fw1[8];
#pragma unroll
  for (int j = 0; j < 8; ++j) {
    fsc[j] = sSc[c0 + j];
    fsh[j] = sSh[c0 + j];
    fw0[j] = sW0[c0 + j];
    fw1[j] = sW1[c0 + j];
  }
  float B0 = b4[0], B1 = b4[1];
  for (size_t row = (size_t)blockIdx.x * 8 + wv * 2; row < (size_t)N;
       row += (size_t)gridDim.x * 8) {
    bf16x8 v0 = *(const bf16x8*)(y3 + row * 512 + c0);
    bf16x8 v1 = *(const bf16x8*)(y3 + (row + 1) * 512 + c0);
    float d0a = 0.f, d1a = 0.f, d0b = 0.f, d1b = 0.f;
#pragma unroll
    for (int j = 0; j < 8; ++j) {
      float ha = fmaxf(fmaf(fsc[j], (float)v0[j], fsh[j]), 0.f);
      float hb = fmaxf(fmaf(fsc[j], (float)v1[j], fsh[j]), 0.f);
      d0a = fmaf(ha, fw0[j], d0a);
      d1a = fmaf(ha, fw1[j], d1a);
      d0b = fmaf(hb, fw0[j], d0b);
      d1b = fmaf(hb, fw1[j], d1b);
    }
    float t0 = d0a + __shfl_xor(d0a, 1);
    float t1 = d1a + __shfl_xor(d1a, 1);
    float t2 = d0b + __shfl_xor(d0b, 1);
    float t3 = d1b + __shfl_xor(d1b, 1);
    float u0 = (lane & 1) ? t1 : t0;
    float u1 = (lane & 1) ? t3 : t2;
    u0 += __shfl_xor(u0, 2);
    u1 += __shfl_xor(u1, 2);
    float w = (lane & 2) ? u1 : u0;
    w += __shfl_xor(w, 4);
    w += __shfl_xor(w, 8);
    w += __shfl_xor(w, 16);
    w += __shfl_xor(w, 32);
    if (lane < 4) out[row * 2 + lane] = w + ((lane & 1) ? B1 : B0);
  }
}

// ---------------------------------------------------------------------------
extern "C" void kernel_launch(void* const* d_in, const int* in_sizes, int n_in,
                              void* d_out, int out_size, void* d_ws,
                              size_t ws_size, hipStream_t stream) {
  const float* x2 = (const float*)d_in[1];
  const float* W1 = (const float*)d_in[2];
  const float* b1 = (const float*)d_in[3];
  const float* W2 = (const float*)d_in[4];
  const float* b2 = (const float*)d_in[5];
  const float* W3 = (const float*)d_in[6];
  const float* b3 = (const float*)d_in[7];
  const float* W4 = (const float*)d_in[8];
  const float* b4 = (const float*)d_in[9];
  const float* gamma1 = (const float*)d_in[10];
  const float* beta1 = (const float*)d_in[11];
  const float* gamma2 = (const float*)d_in[12];
  const float* beta2 = (const float*)d_in[13];
  const float* gamma3 = (const float*)d_in[14];
  const float* beta3 = (const float*)d_in[15];
  float* out = (float*)d_out;

  const int N = in_sizes[1] / 3;  // 262144
  const float invN = 1.0f / (float)N;
  const float fN = (float)N;

  // --- small scratch layout ---
  float* f0 = (float*)d_ws;
  float* xmom = f0;            // 16 (9 used)
  float* M1 = f0 + 16;         // 4096
  float* s1 = f0 + 4112;       // 64
  float* gsum3 = f0 + 4176;    // 512
  float* gsq3 = f0 + 4688;     // 512  (zeroed region: 5200 floats)
  float* scale2 = f0 + 5200;   // 512
  float* shift2f = f0 + 5712;  // 512
  __bf16* W2bf = (__bf16*)(f0 + 6224);  // 32768 elems
  __bf16* W3bf = W2bf + 32768;          // 262144 elems

  // --- adaptive y3 cache ---
  const size_t y3off = (size_t)1 << 20;
  size_t availRows = (ws_size > y3off) ? (ws_size - y3off) / 1024 : 0;
  int rStoreBlks = (int)((availRows / 1024 < (size_t)(N / 1024))
                             ? availRows / 1024
                             : (size_t)(N / 1024));
  const int rStore = rStoreBlks * 1024;
  __bf16* y3bf = (__bf16*)((char*)d_ws + y3off);

  hipMemsetAsync(f0, 0, 5200 * sizeof(float), stream);
  prep_xmom_kernel<<<208, 256, 0, stream>>>(x2, W2, W3, W2bf, W3bf, xmom);
  m1_kernel<<<N / 256, 256, 0, stream>>>(x2, xmom, gamma1, beta1, W1, b1, M1,
                                         s1, invN, fN);
  finalize2v_kernel<<<128, 256, 0, stream>>>(M1, s1, W2, b2, gamma2, beta2,
                                             scale2, shift2f, fN);

  // pass 1: stats (+ y3 store where it fits), 16 row-groups per block,
  // ONE 16-wave block per rowBlk covers all 512 cols. grid = 256 = 1/CU.
  fused_kernel<3><<<N / 1024, 1024, 0, stream>>>(
      x2, xmom, gamma1, beta1, W1, b1, W2bf, scale2, shift2f, W3bf, b3,
      gamma3, beta3, W4, b4, gsum3, gsq3, out, y3bf, 0, 16, rStoreBlks * 16,
      invN, fN);

  // pass 2a: stream stored rows (BN3 finalize inline)
  if (rStore > 0)
    stream_out_kernel<<<2048, 256, 0, stream>>>(y3bf, gsum3, gsq3, gamma3,
                                                beta3, W4, b4, out, rStore,
                                                invN);
  // pass 2b: recompute remainder, ONE row-group per block (plain stores)
  if (rStore < N) {
    fused_kernel<2><<<(N - rStore) / 64, 1024, 0, stream>>>(
        x2, xmom, gamma1, beta1, W1, b1, W2bf, scale2, shift2f, W3bf, b3,
        gamma3, beta3, W4, b4, gsum3, gsq3, out, y3bf, rStore / 64, 1, 0,
        invN, fN);
  }
}

// Round 17
// 324.252 us; speedup vs baseline: 1.6044x; 1.6044x over previous
//
#include <hip/hip_runtime.h>

typedef __bf16 bf16x4 __attribute__((ext_vector_type(4)));
typedef __bf16 bf16x8 __attribute__((ext_vector_type(8)));
typedef float f32x4 __attribute__((ext_vector_type(4)));

#define MFMA_BF16 __builtin_amdgcn_mfma_f32_16x16x32_bf16

// ---------------------------------------------------------------------------
// prep_xmom: blocks [0,64) accumulate x-moments (Sx[3], Sxx[6]);
// blocks [64,80) convert W2->bf16; [80,208) convert W3->bf16.
// ---------------------------------------------------------------------------
__global__ __launch_bounds__(256) void prep_xmom_kernel(
    const float* __restrict__ x, const float* __restrict__ W2,
    const float* __restrict__ W3, __bf16* __restrict__ W2bf,
    __bf16* __restrict__ W3bf, float* __restrict__ xmom) {
  const int b = blockIdx.x;
  const int t = threadIdx.x;
  if (b >= 64) {
    const float* src;
    __bf16* dst;
    int idx;
    if (b < 80) {
      idx = (b - 64) * 2048 + t * 8;
      src = W2;
      dst = W2bf;
    } else {
      idx = (b - 80) * 2048 + t * 8;
      src = W3;
      dst = W3bf;
    }
    float4 f0 = *(const float4*)(src + idx);
    float4 f1 = *(const float4*)(src + idx + 4);
    bf16x8 o;
    o[0] = (__bf16)f0.x;
    o[1] = (__bf16)f0.y;
    o[2] = (__bf16)f0.z;
    o[3] = (__bf16)f0.w;
    o[4] = (__bf16)f1.x;
    o[5] = (__bf16)f1.y;
    o[6] = (__bf16)f1.z;
    o[7] = (__bf16)f1.w;
    *(bf16x8*)(dst + idx) = o;
    return;
  }
  float m[9] = {};
#pragma unroll 4
  for (int i = 0; i < 16; ++i) {
    int r = b * 4096 + i * 256 + t;
    const float* xp = x + (size_t)r * 3;
    float a = xp[0], bb = xp[1], c = xp[2];
    m[0] += a;
    m[1] += bb;
    m[2] += c;
    m[3] = fmaf(a, a, m[3]);
    m[4] = fmaf(a, bb, m[4]);
    m[5] = fmaf(a, c, m[5]);
    m[6] = fmaf(bb, bb, m[6]);
    m[7] = fmaf(bb, c, m[7]);
    m[8] = fmaf(c, c, m[8]);
  }
  __shared__ float red[4][9];
  int lane = t & 63, wave = t >> 6;
#pragma unroll
  for (int j = 0; j < 9; ++j) {
    float v = m[j];
    v += __shfl_xor(v, 1);
    v += __shfl_xor(v, 2);
    v += __shfl_xor(v, 4);
    v += __shfl_xor(v, 8);
    v += __shfl_xor(v, 16);
    v += __shfl_xor(v, 32);
    if (lane == 0) red[wave][j] = v;
  }
  __syncthreads();
  if (t < 9) atomicAdd(&xmom[t], red[0][t] + red[1][t] + red[2][t] + red[3][t]);
}

// compute BN1 fold coeffs for column c (c < 64) from x-moments
__device__ __forceinline__ void bn1_fold(const float* __restrict__ xm,
                                         const float* __restrict__ W1,
                                         const float* __restrict__ b1,
                                         const float* __restrict__ gamma1,
                                         const float* __restrict__ beta1,
                                         int c, float invN, float fN,
                                         float* f0, float* f1, float* f2,
                                         float* f3) {
  float w0 = W1[c * 3], w1 = W1[c * 3 + 1], w2 = W1[c * 3 + 2], bb = b1[c];
  float wx = w0 * xm[0] + w1 * xm[1] + w2 * xm[2];
  float sy = wx + fN * bb;
  float q = w0 * w0 * xm[3] + 2.f * w0 * w1 * xm[4] + 2.f * w0 * w2 * xm[5] +
            w1 * w1 * xm[6] + 2.f * w1 * w2 * xm[7] + w2 * w2 * xm[8] +
            2.f * bb * wx + fN * bb * bb;
  float mu = sy * invN;
  float var = q * invN - mu * mu;
  float sc = gamma1[c] * rsqrtf(var + 1e-5f);
  float sh = beta1[c] - mu * sc;
  *f0 = sc * w0;
  *f1 = sc * w1;
  *f2 = sc * w2;
  *f3 = sc * bb + sh;
}

// ---------------------------------------------------------------------------
// m1: M1 = sum_r h1_r h1_r^T (64x64), s1 = sum_r h1_r. BN1 from moments.
// ---------------------------------------------------------------------------
__global__ __launch_bounds__(256, 4) void m1_kernel(
    const float* __restrict__ x2, const float* __restrict__ xmom,
    const float* __restrict__ gamma1, const float* __restrict__ beta1,
    const float* __restrict__ W1, const float* __restrict__ b1,
    float* __restrict__ M1, float* __restrict__ s1, float invN, float fN) {
  __shared__ float sF[256];
  __shared__ float xs[768];
  __shared__ __bf16 h1T[64 * 264];  // [col][row], row-pad 264
  __shared__ float s1s[4][64];

  const int t = threadIdx.x;
  const int lane = t & 63, wave = t >> 6;
  const int lrow = lane & 15, lgrp = lane >> 4;

  if (t < 64) {
    float f0, f1, f2, f3;
    bn1_fold(xmom, W1, b1, gamma1, beta1, t, invN, fN, &f0, &f1, &f2, &f3);
    sF[t] = f0;
    sF[64 + t] = f1;
    sF[128 + t] = f2;
    sF[192 + t] = f3;
  }
  if (t < 192)
    ((float4*)xs)[t] = ((const float4*)(x2 + (size_t)blockIdx.x * 768))[t];
  __syncthreads();

  const int c0 = (t & 3) * 16;
  const int r0 = t >> 2;
  float sAcc[16] = {};
#pragma unroll
  for (int s = 0; s < 4; ++s) {
    int r = r0 + s * 64;
    float X0 = xs[r * 3], X1 = xs[r * 3 + 1], X2 = xs[r * 3 + 2];
#pragma unroll
    for (int j = 0; j < 16; ++j) {
      int c = c0 + j;
      float h = fmaxf(
          fmaf(sF[c], X0, fmaf(sF[64 + c], X1, fmaf(sF[128 + c], X2, sF[192 + c]))),
          0.f);
      sAcc[j] += h;
      h1T[c * 264 + r] = (__bf16)h;
    }
  }
  __syncthreads();

  f32x4 acc[4] = {};
#pragma unroll
  for (int kk = 0; kk < 256; kk += 32) {
    bf16x8 af = *(const bf16x8*)&h1T[(wave * 16 + lrow) * 264 + kk + lgrp * 8];
#pragma unroll
    for (int n = 0; n < 4; ++n) {
      bf16x8 bfr = *(const bf16x8*)&h1T[(n * 16 + lrow) * 264 + kk + lgrp * 8];
      acc[n] = MFMA_BF16(af, bfr, acc[n], 0, 0, 0);
    }
  }
#pragma unroll
  for (int n = 0; n < 4; ++n)
#pragma unroll
    for (int rr = 0; rr < 4; ++rr)
      atomicAdd(&M1[(wave * 16 + lgrp * 4 + rr) * 64 + n * 16 + lrow],
                acc[n][rr]);

#pragma unroll
  for (int j = 0; j < 16; ++j) {
    float v = sAcc[j];
    v += __shfl_xor(v, 4);
    v += __shfl_xor(v, 8);
    v += __shfl_xor(v, 16);
    v += __shfl_xor(v, 32);
    if (lane < 4) s1s[wave][(lane & 3) * 16 + j] = v;
  }
  __syncthreads();
  if (t < 64)
    atomicAdd(&s1[t], s1s[0][t] + s1s[1][t] + s1s[2][t] + s1s[3][t]);
}

// ---------------------------------------------------------------------------
// finalize2v: per col c of layer 2, q = w^T M1 w; derive BN2 scale/shiftf.
// ---------------------------------------------------------------------------
__global__ __launch_bounds__(256) void finalize2v_kernel(
    const float* __restrict__ M1, const float* __restrict__ s1,
    const float* __restrict__ W2, const float* __restrict__ b2,
    const float* __restrict__ gamma2, const float* __restrict__ beta2,
    float* __restrict__ scale2, float* __restrict__ shift2f, float fN) {
  __shared__ float sM[64 * 65];
  __shared__ float ss[64];
  int t = threadIdx.x;
  for (int i = t; i < 4096; i += 256) sM[(i >> 6) * 65 + (i & 63)] = M1[i];
  if (t < 64) ss[t] = s1[t];
  __syncthreads();
  int lane = t & 63;
  int col = blockIdx.x * 4 + (t >> 6);
  float wi = W2[(size_t)col * 64 + lane];
  float p = 0.f;
#pragma unroll
  for (int j = 0; j < 64; ++j) p = fmaf(sM[lane * 65 + j], __shfl(wi, j), p);
  float qi = wi * p;
  float swi = ss[lane] * wi;
#pragma unroll
  for (int off = 1; off < 64; off <<= 1) {
    qi += __shfl_xor(qi, off);
    swi += __shfl_xor(swi, off);
  }
  if (lane == 0) {
    float b = b2[col];
    float sy = swi + fN * b;
    float sqs = qi + 2.f * b * swi + fN * b * b;
    float mu = sy / fN;
    float var = sqs / fN - mu * mu;
    float sc = gamma2[col] * rsqrtf(var + 1e-5f);
    scale2[col] = sc;
    shift2f[col] = (beta2[col] - mu * sc) + sc * b;
  }
}

// ---------------------------------------------------------------------------
// Fused kernel: register-resident W2/W3, ONE barrier per row-group,
// double-buffered h1/h2, lockstep order (skew refuted r12/r13; 16-wave
// refuted r16 — 4 waves/SIMD caps 128 regs/wave < W3-resident needs):
//   gemm2(g+1) -> h2[(g+1)&1];  stageH1(g+2) -> h1[g&1];  gemm3(g); epilogue.
// MODE 3: stats + store y3 bf16 where (rgFirst+g) < rStoreRgs.
// MODE 2 (gCount==1): BN3 (inline from stats3) + ReLU + @W4 -> out.
// ---------------------------------------------------------------------------
#define G3_LD(BUF, K)                                                        \
  _Pragma("unroll") for (int m = 0; m < 4; ++m) BUF[m] =                     \
      *(const bf16x8*)&h2r[(m * 16 + lrow) * 520 + (K) * 32 + lgrp * 8];

#define G3_MM(BUF, K)                                                        \
  _Pragma("unroll") for (int m = 0; m < 4; ++m) {                            \
    acc[m][0] = MFMA_BF16(BUF[m], b3r[K][0], acc[m][0], 0, 0, 0);            \
    acc[m][1] = MFMA_BF16(BUF[m], b3r[K][1], acc[m][1], 0, 0, 0);            \
  }

template <int MODE>
__global__ __launch_bounds__(512, 2) void fused_kernel(
    const float* __restrict__ x2, const float* __restrict__ xmom,
    const float* __restrict__ gamma1, const float* __restrict__ beta1,
    const float* __restrict__ W1, const float* __restrict__ b1,
    const __bf16* __restrict__ W2bf, const float* __restrict__ scale2,
    const float* __restrict__ shift2f, const __bf16* __restrict__ W3bf,
    const float* __restrict__ b3, const float* __restrict__ gamma3,
    const float* __restrict__ beta3, const float* __restrict__ W4,
    const float* __restrict__ b4, float* __restrict__ gsum3,
    float* __restrict__ gsq3, float* __restrict__ out,
    __bf16* __restrict__ y3o, int gBase, int gCount, int rStoreRgs,
    float invN, float fN) {
  __shared__ __bf16 h1buf[2][64 * 72];   // 2 x 9 KB
  __shared__ __bf16 h2buf[2][64 * 520];  // 2 x 65 KB
  __shared__ float sF[256];
  __shared__ float sSc2[512], sSh2[512];
  __shared__ float outaccW[8][64][2];    // 4 KB (MODE 2)

  const int t = threadIdx.x;
  const int lane = t & 63, wave = t >> 6;
  const int lrow = lane & 15, lgrp = lane >> 4;
  const int colHalf = blockIdx.x & 1;
  const int rgFirst = gBase + (int)(blockIdx.x >> 1) * gCount;
  const int wCol3 = colHalf * 256 + wave * 32;
  const int wCol2 = wave * 64;

  // ---- one-time LDS staging (BN1 fold from x-moments) ----
  if (t < 64) {
    float f0, f1, f2, f3;
    bn1_fold(xmom, W1, b1, gamma1, beta1, t, invN, fN, &f0, &f1, &f2, &f3);
    sF[t] = f0;
    sF[64 + t] = f1;
    sF[128 + t] = f2;
    sF[192 + t] = f3;
  }
  sSc2[t] = scale2[t & 511];
  sSh2[t] = shift2f[t & 511];

  // ---- one-time: W2, W3 fragments -> registers ----
  bf16x8 b2r[2][4];
#pragma unroll
  for (int kk = 0; kk < 2; ++kk)
#pragma unroll
    for (int n = 0; n < 4; ++n)
      b2r[kk][n] = *(const bf16x8*)&W2bf[(wCol2 + n * 16 + lrow) * 64 +
                                         kk * 32 + lgrp * 8];
  bf16x8 b3r[16][2];
#pragma unroll
  for (int k = 0; k < 16; ++k)
#pragma unroll
    for (int n = 0; n < 2; ++n)
      b3r[k][n] = *(const bf16x8*)&W3bf[(size_t)(wCol3 + n * 16 + lrow) * 512 +
                                        k * 32 + lgrp * 8];

  const int c3a = wCol3 + lrow, c3b = wCol3 + 16 + lrow;
  float b3a = 0.f, b3b = 0.f;
  float sc3a = 0.f, sc3b = 0.f, sh3a = 0.f, sh3b = 0.f;
  float w40a = 0.f, w40b = 0.f, w41a = 0.f, w41b = 0.f, B40 = 0.f, B41 = 0.f;
  if (MODE != 2) {
    b3a = b3[c3a];
    b3b = b3[c3b];
  } else {
    float mu = gsum3[c3a] * invN;
    float var = gsq3[c3a] * invN - mu * mu;
    sc3a = gamma3[c3a] * rsqrtf(var + 1e-5f);
    sh3a = sc3a * b3[c3a] + (beta3[c3a] - mu * sc3a);
    mu = gsum3[c3b] * invN;
    var = gsq3[c3b] * invN - mu * mu;
    sc3b = gamma3[c3b] * rsqrtf(var + 1e-5f);
    sh3b = sc3b * b3[c3b] + (beta3[c3b] - mu * sc3b);
    w40a = W4[c3a];
    w40b = W4[c3b];
    w41a = W4[512 + c3a];
    w41b = W4[512 + c3b];
    B40 = b4[0];
    B41 = b4[1];
  }
  float csA = 0.f, cqA = 0.f, csB = 0.f, cqB = 0.f;

  const int hr = t >> 3, hc0 = (t & 7) * 8;
  const float* xbase = x2 + ((size_t)rgFirst * 64 + hr) * 3;
  float xa, xb, xc;

  auto stageH1 = [&](__bf16* h1p) {
    bf16x8 hv;
#pragma unroll
    for (int j = 0; j < 8; ++j) {
      int c = hc0 + j;
      float h = fmaf(sF[c], xa,
                     fmaf(sF[64 + c], xb, fmaf(sF[128 + c], xc, sF[192 + c])));
      hv[j] = (__bf16)fmaxf(h, 0.f);
    }
    *(bf16x8*)&h1p[hr * 72 + hc0] = hv;
  };

  auto gemm2 = [&](const __bf16* h1p, __bf16* h2p) {
#pragma unroll
    for (int nh = 0; nh < 2; ++nh) {
      f32x4 a2[2][4] = {};  // [n2][m]
#pragma unroll
      for (int kk = 0; kk < 2; ++kk) {
        bf16x8 af0 = *(const bf16x8*)&h1p[(0 * 16 + lrow) * 72 + kk * 32 + lgrp * 8];
        bf16x8 af1 = *(const bf16x8*)&h1p[(1 * 16 + lrow) * 72 + kk * 32 + lgrp * 8];
        bf16x8 af2 = *(const bf16x8*)&h1p[(2 * 16 + lrow) * 72 + kk * 32 + lgrp * 8];
        bf16x8 af3 = *(const bf16x8*)&h1p[(3 * 16 + lrow) * 72 + kk * 32 + lgrp * 8];
#pragma unroll
        for (int n2 = 0; n2 < 2; ++n2) {
          int n = nh * 2 + n2;
          a2[n2][0] = MFMA_BF16(b2r[kk][n], af0, a2[n2][0], 0, 0, 0);
          a2[n2][1] = MFMA_BF16(b2r[kk][n], af1, a2[n2][1], 0, 0, 0);
          a2[n2][2] = MFMA_BF16(b2r[kk][n], af2, a2[n2][2], 0, 0, 0);
          a2[n2][3] = MFMA_BF16(b2r[kk][n], af3, a2[n2][3], 0, 0, 0);
        }
      }
#pragma unroll
      for (int n2 = 0; n2 < 2; ++n2) {
        int ch0 = wCol2 + (nh * 2 + n2) * 16 + lgrp * 4;
        float s0 = sSc2[ch0], s1v = sSc2[ch0 + 1], s2v = sSc2[ch0 + 2],
              s3v = sSc2[ch0 + 3];
        float z0 = sSh2[ch0], z1 = sSh2[ch0 + 1], z2 = sSh2[ch0 + 2],
              z3 = sSh2[ch0 + 3];
#pragma unroll
        for (int m = 0; m < 4; ++m) {
          int row = m * 16 + lrow;
          bf16x4 hv;
          hv[0] = (__bf16)fmaxf(fmaf(s0, a2[n2][m][0], z0), 0.f);
          hv[1] = (__bf16)fmaxf(fmaf(s1v, a2[n2][m][1], z1), 0.f);
          hv[2] = (__bf16)fmaxf(fmaf(s2v, a2[n2][m][2], z2), 0.f);
          hv[3] = (__bf16)fmaxf(fmaf(s3v, a2[n2][m][3], z3), 0.f);
          *(bf16x4*)&h2p[row * 520 + ch0] = hv;
        }
      }
    }
  };

  __syncthreads();  // sF/sSc2/sSh2 visible

  // ---- prologue ----
  xa = xbase[0];
  xb = xbase[1];
  xc = xbase[2];
  stageH1(h1buf[0]);
  __syncthreads();  // h1(0) ready
  gemm2(h1buf[0], h2buf[0]);
  if (gCount > 1) {
    const float* xn = xbase + 192;
    xa = xn[0];
    xb = xn[1];
    xc = xn[2];
    stageH1(h1buf[1]);
  }
  __syncthreads();  // h2(0) + h1(1) ready

  for (int g = 0; g < gCount; ++g) {
    const int rBase = (rgFirst + g) * 64;
    const __bf16* h2r = h2buf[g & 1];
    const bool doStore = (MODE == 3) && (rgFirst + g < rStoreRgs);

    // issue x loads for h1(g+2) early
    if (g + 2 < gCount) {
      const float* xn = xbase + (size_t)(g + 2) * 192;
      xa = xn[0];
      xb = xn[1];
      xc = xn[2];
    }

    // GEMM2(g+1) -> h2[(g+1)&1]
    if (g + 1 < gCount) gemm2(h1buf[(g + 1) & 1], h2buf[(g + 1) & 1]);

    // stage h1(g+2) -> h1[g&1]
    if (g + 2 < gCount) stageH1(h1buf[g & 1]);

    // ---- GEMM3(g): 2-deep af pipeline, register-B MFMA ----
    f32x4 acc[4][2] = {};  // [m][n]
    bf16x8 afA[4], afB[4];
    G3_LD(afA, 0)
#pragma unroll
    for (int k = 0; k < 16; k += 2) {
      G3_LD(afB, k + 1)
      G3_MM(afA, k)
      if (k < 14) { G3_LD(afA, k + 2) }
      G3_MM(afB, k + 1)
    }

    if (MODE != 2) {
#pragma unroll
      for (int m = 0; m < 4; ++m)
#pragma unroll
        for (int rr = 0; rr < 4; ++rr) {
          float ya = acc[m][0][rr] + b3a;
          float yb = acc[m][1][rr] + b3b;
          csA += ya;
          cqA = fmaf(ya, ya, cqA);
          csB += yb;
          cqB = fmaf(yb, yb, cqB);
          if (doStore) {
            size_t row = (size_t)(rBase + m * 16 + lgrp * 4 + rr);
            y3o[row * 512 + c3a] = (__bf16)ya;
            y3o[row * 512 + c3b] = (__bf16)yb;
          }
        }
    } else {
#pragma unroll
      for (int m = 0; m < 4; ++m)
#pragma unroll
        for (int rr = 0; rr < 4; ++rr) {
          float ha = fmaxf(fmaf(sc3a, acc[m][0][rr], sh3a), 0.f);
          float hb = fmaxf(fmaf(sc3b, acc[m][1][rr], sh3b), 0.f);
          float dd0 = fmaf(ha, w40a, hb * w40b);
          float dd1 = fmaf(ha, w41a, hb * w41b);
          dd0 += __shfl_xor(dd0, 1);
          dd1 += __shfl_xor(dd1, 1);
          dd0 += __shfl_xor(dd0, 2);
          dd1 += __shfl_xor(dd1, 2);
          dd0 += __shfl_xor(dd0, 4);
          dd1 += __shfl_xor(dd1, 4);
          dd0 += __shfl_xor(dd0, 8);
          dd1 += __shfl_xor(dd1, 8);
          if (lrow == 0) {
            int row = m * 16 + lgrp * 4 + rr;
            outaccW[wave][row][0] = dd0;
            outaccW[wave][row][1] = dd1;
          }
        }
    }
    __syncthreads();  // single per-rg barrier: all buffers rotate safely
  }

  if (MODE != 2) {
    csA += __shfl_xor(csA, 16);
    cqA += __shfl_xor(cqA, 16);
    csB += __shfl_xor(csB, 16);
    cqB += __shfl_xor(cqB, 16);
    csA += __shfl_xor(csA, 32);
    cqA += __shfl_xor(cqA, 32);
    csB += __shfl_xor(csB, 32);
    cqB += __shfl_xor(cqB, 32);
    if (lgrp == 0) {
      atomicAdd(&gsum3[c3a], csA);
      atomicAdd(&gsq3[c3a], cqA);
      atomicAdd(&gsum3[c3b], csB);
      atomicAdd(&gsq3[c3b], cqB);
    }
  } else {
    // gCount == 1: reduce outaccW after the loop barrier
    if (t < 128) {
      int row = t >> 1, o = t & 1;
      float s = 0.f;
#pragma unroll
      for (int w = 0; w < 8; ++w) s += outaccW[w][row][o];
      if (colHalf == 0) s += (o == 0) ? B40 : B41;
      atomicAdd(&out[(size_t)(rgFirst * 64 + row) * 2 + o], s);
    }
  }
}

// ---------------------------------------------------------------------------
// stream_out: out = relu(sc3*y3 + sh3) @ W4^T + b4. BN3 finalize inline.
// ---------------------------------------------------------------------------
__global__ __launch_bounds__(256) void stream_out_kernel(
    const __bf16* __restrict__ y3, const float* __restrict__ gsum3,
    const float* __restrict__ gsq3, const float* __restrict__ gamma3,
    const float* __restrict__ beta3, const float* __restrict__ W4,
    const float* __restrict__ b4, float* __restrict__ out, int N, float invN) {
  __shared__ float sSc[512], sSh[512], sW0[512], sW1[512];
  int t = threadIdx.x;
  for (int i = t; i < 512; i += 256) {
    float mu = gsum3[i] * invN;
    float var = gsq3[i] * invN - mu * mu;
    float sc = gamma3[i] * rsqrtf(var + 1e-5f);
    sSc[i] = sc;
    sSh[i] = beta3[i] - mu * sc;  // y3 already includes b3
    sW0[i] = W4[i];
    sW1[i] = W4[512 + i];
  }
  __syncthreads();
  int lane = t & 63, wv = t >> 6;
  int c0 = lane * 8;
  float fsc[8], fsh[8], fw0[8], fw1[8];
#pragma unroll
  for (int j = 0; j < 8; ++j) {
    fsc[j] = sSc[c0 + j];
    fsh[j] = sSh[c0 + j];
    fw0[j] = sW0[c0 + j];
    fw1[j] = sW1[c0 + j];
  }
  float B0 = b4[0], B1 = b4[1];
  for (size_t row = (size_t)blockIdx.x * 8 + wv * 2; row < (size_t)N;
       row += (size_t)gridDim.x * 8) {
    bf16x8 v0 = *(const bf16x8*)(y3 + row * 512 + c0);
    bf16x8 v1 = *(const bf16x8*)(y3 + (row + 1) * 512 + c0);
    float d0a = 0.f, d1a = 0.f, d0b = 0.f, d1b = 0.f;
#pragma unroll
    for (int j = 0; j < 8; ++j) {
      float ha = fmaxf(fmaf(fsc[j], (float)v0[j], fsh[j]), 0.f);
      float hb = fmaxf(fmaf(fsc[j], (float)v1[j], fsh[j]), 0.f);
      d0a = fmaf(ha, fw0[j], d0a);
      d1a = fmaf(ha, fw1[j], d1a);
      d0b = fmaf(hb, fw0[j], d0b);
      d1b = fmaf(hb, fw1[j], d1b);
    }
    float t0 = d0a + __shfl_xor(d0a, 1);
    float t1 = d1a + __shfl_xor(d1a, 1);
    float t2 = d0b + __shfl_xor(d0b, 1);
    float t3 = d1b + __shfl_xor(d1b, 1);
    float u0 = (lane & 1) ? t1 : t0;
    float u1 = (lane & 1) ? t3 : t2;
    u0 += __shfl_xor(u0, 2);
    u1 += __shfl_xor(u1, 2);
    float w = (lane & 2) ? u1 : u0;
    w += __shfl_xor(w, 4);
    w += __shfl_xor(w, 8);
    w += __shfl_xor(w, 16);
    w += __shfl_xor(w, 32);
    if (lane < 4) out[row * 2 + lane] = w + ((lane & 1) ? B1 : B0);
  }
}

// ---------------------------------------------------------------------------
extern "C" void kernel_launch(void* const* d_in, const int* in_sizes, int n_in,
                              void* d_out, int out_size, void* d_ws,
                              size_t ws_size, hipStream_t stream) {
  const float* x2 = (const float*)d_in[1];
  const float* W1 = (const float*)d_in[2];
  const float* b1 = (const float*)d_in[3];
  const float* W2 = (const float*)d_in[4];
  const float* b2 = (const float*)d_in[5];
  const float* W3 = (const float*)d_in[6];
  const float* b3 = (const float*)d_in[7];
  const float* W4 = (const float*)d_in[8];
  const float* b4 = (const float*)d_in[9];
  const float* gamma1 = (const float*)d_in[10];
  const float* beta1 = (const float*)d_in[11];
  const float* gamma2 = (const float*)d_in[12];
  const float* beta2 = (const float*)d_in[13];
  const float* gamma3 = (const float*)d_in[14];
  const float* beta3 = (const float*)d_in[15];
  float* out = (float*)d_out;

  const int N = in_sizes[1] / 3;  // 262144
  const float invN = 1.0f / (float)N;
  const float fN = (float)N;

  // --- small scratch layout ---
  float* f0 = (float*)d_ws;
  float* xmom = f0;            // 16 (9 used)
  float* M1 = f0 + 16;         // 4096
  float* s1 = f0 + 4112;       // 64
  float* gsum3 = f0 + 4176;    // 512
  float* gsq3 = f0 + 4688;     // 512  (zeroed region: 5200 floats)
  float* scale2 = f0 + 5200;   // 512
  float* shift2f = f0 + 5712;  // 512
  __bf16* W2bf = (__bf16*)(f0 + 6224);  // 32768 elems
  __bf16* W3bf = W2bf + 32768;          // 262144 elems

  // --- adaptive y3 cache ---
  const size_t y3off = (size_t)1 << 20;
  size_t availRows = (ws_size > y3off) ? (ws_size - y3off) / 1024 : 0;
  int rStoreBlks = (int)((availRows / 1024 < (size_t)(N / 1024))
                             ? availRows / 1024
                             : (size_t)(N / 1024));
  const int rStore = rStoreBlks * 1024;
  __bf16* y3bf = (__bf16*)((char*)d_ws + y3off);

  hipMemsetAsync(f0, 0, 5200 * sizeof(float), stream);
  prep_xmom_kernel<<<208, 256, 0, stream>>>(x2, W2, W3, W2bf, W3bf, xmom);
  m1_kernel<<<N / 256, 256, 0, stream>>>(x2, xmom, gamma1, beta1, W1, b1, M1,
                                         s1, invN, fN);
  finalize2v_kernel<<<128, 256, 0, stream>>>(M1, s1, W2, b2, gamma2, beta2,
                                             scale2, shift2f, fN);

  // pass 1: stats (+ y3 store where it fits), 32 row-groups per block
  // grid = (N/2048 rowBlks) x 2 colHalves = 256 blocks = exactly 1 per CU
  fused_kernel<3><<<(N / 2048) * 2, 512, 0, stream>>>(
      x2, xmom, gamma1, beta1, W1, b1, W2bf, scale2, shift2f, W3bf, b3,
      gamma3, beta3, W4, b4, gsum3, gsq3, out, y3bf, 0, 32, rStoreBlks * 16,
      invN, fN);

  // pass 2a: stream stored rows (BN3 finalize inline)
  if (rStore > 0)
    stream_out_kernel<<<2048, 256, 0, stream>>>(y3bf, gsum3, gsq3, gamma3,
                                                beta3, W4, b4, out, rStore,
                                                invN);
  // pass 2b: recompute remainder, ONE row-group per block
  if (rStore < N) {
    hipMemsetAsync(out + (size_t)rStore * 2, 0,
                   (size_t)(N - rStore) * 2 * sizeof(float), stream);
    fused_kernel<2><<<((N - rStore) / 64) * 2, 512, 0, stream>>>(
        x2, xmom, gamma1, beta1, W1, b1, W2bf, scale2, shift2f, W3bf, b3,
        gamma3, beta3, W4, b4, gsum3, gsq3, out, y3bf, rStore / 64, 1, 0,
        invN, fN);
  }
}